// Round 13
// baseline (352.698 us; speedup 1.0000x reference)
//
#include <hip/hip_runtime.h>

typedef unsigned short u16;
typedef __attribute__((ext_vector_type(8))) u16    u16x8;
typedef __attribute__((ext_vector_type(4))) u16    u16x4;
typedef __attribute__((ext_vector_type(2))) unsigned u32x2;
typedef __attribute__((ext_vector_type(8))) __bf16 bf16x8;
typedef __attribute__((ext_vector_type(4))) float  f32x4;
typedef __attribute__((ext_vector_type(16))) float f32x16;

#define NBLK 512

__device__ __forceinline__ u16 f2bf(float f) {
    unsigned u = __float_as_uint(f);
    u += 0x7fffu + ((u >> 16) & 1u);   // RNE
    return (u16)(u >> 16);
}
__device__ __forceinline__ bf16x8 ldbf8(const u16* p) {
    return __builtin_bit_cast(bf16x8, *(const u16x8*)p);
}
__device__ __forceinline__ f32x4 mfma16(bf16x8 a, bf16x8 b, f32x4 c) {
    return __builtin_amdgcn_mfma_f32_16x16x32_bf16(a, b, c, 0, 0, 0);
}
__device__ __forceinline__ f32x16 mfma32x(bf16x8 a, bf16x8 b, f32x16 c) {
    return __builtin_amdgcn_mfma_f32_32x32x16_bf16(a, b, c, 0, 0, 0);
}
__device__ __forceinline__ float exp2a(float x) {
    float r; asm("v_exp_f32 %0, %1" : "=v"(r) : "v"(x)); return r;
}
__device__ __forceinline__ unsigned cvtpk(float lo, float hiv) {
    unsigned r; asm("v_cvt_pk_bf16_f32 %0, %1, %2" : "=v"(r) : "v"(lo), "v"(hiv)); return r;
}
__device__ __forceinline__ u32x2 permswap2(unsigned a, unsigned b) {
    return __builtin_amdgcn_permlane32_swap(a, b, false, false);
}
__device__ __forceinline__ float combine_sum(float x) {   // x + partner-half x (orientation-robust)
    u32x2 pr = permswap2(__float_as_uint(x), __float_as_uint(x));
    return __uint_as_float(pr[0]) + __uint_as_float(pr[1]);
}
__device__ __forceinline__ bf16x8 pack4(unsigned a, unsigned b, unsigned c, unsigned d) {
    union { unsigned u[4]; bf16x8 v; } t; t.u[0] = a; t.u[1] = b; t.u[2] = c; t.u[3] = d; return t.v;
}

// ---------------- grid barrier (count-up, one counter per phase, init'd per launch) ----------------
__global__ void init_sync(unsigned* s) { if (threadIdx.x < 16) s[threadIdx.x] = 0; }

__device__ __forceinline__ void gbar(unsigned* c, int tid) {
    __syncthreads();
    if (tid == 0) {
        __threadfence();                                          // release prior writes device-wide
        __hip_atomic_fetch_add(c, 1u, __ATOMIC_ACQ_REL, __HIP_MEMORY_SCOPE_AGENT);
        while (__hip_atomic_load(c, __ATOMIC_ACQUIRE, __HIP_MEMORY_SCOPE_AGENT) < (unsigned)NBLK)
            __builtin_amdgcn_s_sleep(2);
        __threadfence();                                          // acquire: invalidate stale caches
    }
    __syncthreads();
}

// ---------------- phase 0 unit: LN row (u<4096) or 32x32 weight-transpose tile ----------------
__device__ __forceinline__ void prep_unit(char* SMc, int u, int tid,
        const float* __restrict__ x, const float* __restrict__ gamma,
        const float* __restrict__ Wq, const float* __restrict__ Wkv, const float* __restrict__ Wo,
        u16* __restrict__ xn, u16* __restrict__ xb, u16* __restrict__ Wq_t,
        u16* __restrict__ Wkv_t, u16* __restrict__ Wo_t, float qscale) {
    __syncthreads();                                  // prior unit's SM reads done
    if (u < 4096) {
        float* red = (float*)SMc;                     // 8 floats
        const int row = u;
        const float4 v = ((const float4*)(x + (size_t)row * 1024))[tid];
        float s  = v.x + v.y + v.z + v.w;
        float s2 = v.x * v.x + v.y * v.y + v.z * v.z + v.w * v.w;
#pragma unroll
        for (int off = 32; off; off >>= 1) { s += __shfl_down(s, off); s2 += __shfl_down(s2, off); }
        const int w = tid >> 6, lane = tid & 63;
        if (lane == 0) { red[w] = s; red[4 + w] = s2; }
        __syncthreads();
        s  = red[0] + red[1] + red[2] + red[3];
        s2 = red[4] + red[5] + red[6] + red[7];
        const float mu  = s * (1.0f / 1024.0f);
        const float var = s2 * (1.0f / 1024.0f) - mu * mu;
        const float rs  = rsqrtf(var + 1e-5f);
        const float4 g = ((const float4*)gamma)[tid];
        u16x4 on, ob;
        on.x = f2bf((v.x - mu) * rs * g.x); on.y = f2bf((v.y - mu) * rs * g.y);
        on.z = f2bf((v.z - mu) * rs * g.z); on.w = f2bf((v.w - mu) * rs * g.w);
        ob.x = f2bf(v.x); ob.y = f2bf(v.y); ob.z = f2bf(v.z); ob.w = f2bf(v.w);
        ((u16x4*)(xn + (size_t)row * 1024))[tid] = on;
        ((u16x4*)(xb + (size_t)row * 1024))[tid] = ob;
    } else {
        float (*tile)[33] = (float(*)[33])SMc;        // 4224B
        int bt = u - 4096;
        int by = bt >> 5;
        const float* W; u16* Wt; int N; float scale;
        if (by < 32)      { W = Wq;  Wt = Wq_t;  N = 1024; scale = qscale; }
        else if (by < 36) { W = Wkv; Wt = Wkv_t; N = 128;  by -= 32; scale = 1.0f; }
        else              { W = Wo;  Wt = Wo_t;  N = 1024; by -= 36; scale = 1.0f; }
        const int K = 1024;
        const int kb = (bt & 31) * 32, nb = by * 32;
        const int tx = tid & 31, ty = tid >> 5;       // (32, 8)
#pragma unroll
        for (int i = 0; i < 32; i += 8)
            tile[ty + i][tx] = W[(size_t)(kb + ty + i) * N + nb + tx];
        __syncthreads();
#pragma unroll
        for (int i = 0; i < 32; i += 8)
            Wt[(size_t)(nb + ty + i) * K + kb + tx] = f2bf(tile[tx][ty + i] * scale);
    }
}

// ---------------- GEMM core: C[M,N] = A[M,K] @ Bt[N,K]^T, BM=128 BN=64 BK=64 ----------------
// LDS K-chunks XOR-swizzled (rule 21). EPI 0: bf16 C. EPI 1: f32 C. EPI 2: KV split + kmax partials.
template<int EPI>
__device__ __forceinline__ void gemm_core(u16* lds, float (*kred)[128],
                                          const u16* __restrict__ A, const u16* __restrict__ Bt,
                                          u16* __restrict__ Cb, float* __restrict__ Cf, u16* __restrict__ Cv,
                                          int N, int K, int bx, int by, int tid) {
    constexpr int BM = 128, BN = 64, BK = 64;
    constexpr int WM = 64, WN = 32, FM = 4, FN = 2;
    constexpr int CPR = BK / 8, MS = CPR - 1;         // 8 chunks/row, swizzle mask 7
    constexpr int CHA = BM * CPR, CH = (BM + BN) * CPR, ITERS = CH / 256;
    constexpr int LB = (BM + BN) * BK;                // u16 per buffer
    const int m0 = bx * BM, n0 = by * BN;
    const int w = tid >> 6, lane = tid & 63, cl = lane & 15, kg = lane >> 4;
    const int wr = w >> 1, wc = w & 1;
    __syncthreads();                                  // prior phase/unit SM reads done

    auto stage = [&](int buf, int k0) {
#pragma unroll
        for (int it = 0; it < ITERS; ++it) {
            int c = it * 256 + tid;
            const u16* g;
            if (c < CHA) { int r = c / CPR, cc = c & MS; g = A  + (size_t)(m0 + r) * K + k0 + ((cc ^ (r & MS)) * 8); }
            else { int c2 = c - CHA; int r = c2 / CPR, cc = c2 & MS; g = Bt + (size_t)(n0 + r) * K + k0 + ((cc ^ (r & MS)) * 8); }
            __builtin_amdgcn_global_load_lds(
                (const __attribute__((address_space(1))) unsigned int*)g,
                (__attribute__((address_space(3))) unsigned int*)&lds[buf * LB + c * 8], 16, 0, 0);
        }
    };

    const f32x4 zero = {0.f, 0.f, 0.f, 0.f};
    f32x4 acc[FM][FN];
#pragma unroll
    for (int m = 0; m < FM; m++)
#pragma unroll
        for (int n = 0; n < FN; n++) acc[m][n] = zero;

    const int KT = K / BK;
    stage(0, 0);
    for (int t = 0; t < KT; ++t) {
        __syncthreads();
        if (t + 1 < KT) stage((t + 1) & 1, (t + 1) * BK);
        const u16* As = &lds[(t & 1) * LB];
        const u16* Bs = &lds[(t & 1) * LB + BM * BK];
#pragma unroll
        for (int s = 0; s < BK / 32; s++) {
            bf16x8 af[FM], bfr[FN];
#pragma unroll
            for (int m = 0; m < FM; m++) {
                const int ra = wr * WM + m * 16 + cl;
                af[m] = ldbf8(As + ra * BK + (((s * 4 + kg) ^ (ra & MS)) * 8));
            }
#pragma unroll
            for (int n = 0; n < FN; n++) {
                const int rb = wc * WN + n * 16 + cl;
                bfr[n] = ldbf8(Bs + rb * BK + (((s * 4 + kg) ^ (rb & MS)) * 8));
            }
#pragma unroll
            for (int m = 0; m < FM; m++)
#pragma unroll
                for (int n = 0; n < FN; n++) acc[m][n] = mfma16(af[m], bfr[n], acc[m][n]);
        }
    }

#pragma unroll
    for (int m = 0; m < FM; m++)
#pragma unroll
        for (int n = 0; n < FN; n++)
#pragma unroll
            for (int r = 0; r < 4; r++) {
                const int row = m0 + wr * WM + m * 16 + kg * 4 + r;
                const int col = n0 + wc * WN + n * 16 + cl;
                const float v = acc[m][n][r];
                if constexpr (EPI == 0) Cb[(size_t)row * N + col] = f2bf(v);
                else if constexpr (EPI == 1) Cf[(size_t)row * N + col] = v;
                else {
                    if (col < 64) Cb[(size_t)row * 64 + col] = f2bf(v);
                    else { int bb = row >> 11, s = row & 2047;
                           Cv[((size_t)bb * 64 + (col - 64)) * 2048 + s] = f2bf(v); }
                }
            }

    // fused kmax partials: kpart[bx] = max over this block's 128 rows of ||bf16(k_row)||^2
    if constexpr (EPI == 2) {
        if (n0 == 0) {
            float s2[FM][4];
#pragma unroll
            for (int m = 0; m < FM; m++)
#pragma unroll
                for (int r = 0; r < 4; r++) {
                    float t = 0.f;
#pragma unroll
                    for (int n = 0; n < FN; n++) {
                        const float vb = __uint_as_float(((unsigned)f2bf(acc[m][n][r])) << 16);
                        t = fmaf(vb, vb, t);
                    }
                    s2[m][r] = t;
                }
#pragma unroll
            for (int off = 1; off < 16; off <<= 1)
#pragma unroll
                for (int m = 0; m < FM; m++)
#pragma unroll
                    for (int r = 0; r < 4; r++) s2[m][r] += __shfl_xor(s2[m][r], off);
            if (cl == 0)
#pragma unroll
                for (int m = 0; m < FM; m++)
#pragma unroll
                    for (int r = 0; r < 4; r++) kred[wc][wr * 64 + m * 16 + kg * 4 + r] = s2[m][r];
            __syncthreads();
            if (tid < 64) {
                float t = fmaxf(kred[0][tid] + kred[1][tid], kred[0][tid + 64] + kred[1][tid + 64]);
#pragma unroll
                for (int off = 1; off < 64; off <<= 1) t = fmaxf(t, __shfl_xor(t, off));
                if (tid == 0) Cf[bx] = t;      // Cf = kpart
            }
        }
    }
}

// ---------------- attention unit (identical structure to R12 attn_fwd) ----------------
__device__ __forceinline__ void attn_unit(u16* smem, int bid, int tid,
        const u16* __restrict__ q, const u16* __restrict__ k, const u16* __restrict__ vt,
        const float* __restrict__ kpart, u16* __restrict__ o) {
    constexpr int S = 2048;
    const int p = (bid < 256) ? (bid >> 5) : (15 - ((bid - 256) >> 5));
    const int bh = bid & 31;
    const int h = bh & 15, b = bh >> 4;
    const int w = tid >> 6, lane = tid & 63;
    const int pw = w & 1, par = w >> 1;
    const int l31 = lane & 31;
    const bool hi = (lane & 32) != 0;
    const int hi1 = hi ? 1 : 0, hi8 = hi ? 8 : 0;
    const int t1 = 2 * p + pw, t2 = 63 - t1;
    const int iters = 32 - p;
    const size_t bS = (size_t)b * S;

    auto stageK = [&](int jt, int buf, int tl) {
        const int r = tid >> 3, c = tid & 7;
        const u16* gp = k + (bS + jt * 32 + r) * 64 + ((c ^ (r & 7)) * 8);
        __builtin_amdgcn_global_load_lds(
            (const __attribute__((address_space(1))) unsigned int*)gp,
            (__attribute__((address_space(3))) unsigned int*)(smem + (buf * 2 + tl) * 2048 + tid * 8), 16, 0, 0);
    };
    auto loadV = [&](int jt) -> u16x8 {
        const int rv = tid >> 2, c4 = tid & 3;
        return *(const u16x8*)(vt + ((size_t)b * 64 + rv) * S + jt * 32 + c4 * 8);
    };
    auto writeV = [&](int buf, int tl, u16x8 v) {
        const int rv = tid >> 2, c4 = tid & 3;
        *(u16x8*)(smem + 8192 + (buf * 2 + tl) * 2560 + rv * 40 + c4 * 8) = v;
    };

    float km = kpart[(b << 4) + (l31 & 15)];
#pragma unroll
    for (int off = 1; off < 16; off <<= 1) km = fmaxf(km, __shfl_xor(km, off));
    const float kmaxb = sqrtf(km);

    bf16x8 qf1[4], qf2[4];
    float mB1, mB2;
    auto qload = [&](int t, bf16x8 (&qf)[4]) -> float {
        const u16* qp = q + (bS + t * 32 + l31) * 1024 + h * 64 + hi8;
        float qn2 = 0.f;
#pragma unroll
        for (int sub = 0; sub < 4; sub++) {
            qf[sub] = ldbf8(qp + sub * 16);
            const u16x8 uv = __builtin_bit_cast(u16x8, qf[sub]);
#pragma unroll
            for (int j = 0; j < 8; j++) {
                const float v = __uint_as_float(((unsigned)uv[j]) << 16);
                qn2 = fmaf(v, v, qn2);
            }
        }
        return sqrtf(combine_sum(qn2)) * kmaxb;
    };
    mB1 = qload(t1, qf1);
    mB2 = qload(t2, qf2);

    f32x16 a1lo, a1hi, a2lo, a2hi;
#pragma unroll
    for (int r = 0; r < 16; r++) { a1lo[r] = 0.f; a1hi[r] = 0.f; a2lo[r] = 0.f; a2hi[r] = 0.f; }
    float l1 = 0.f, l2 = 0.f;

    auto process = [&](const bf16x8 (&qf)[4], const bf16x8 (&kf)[4],
                       const bf16x8& vf00, const bf16x8& vf01, const bf16x8& vf10, const bf16x8& vf11,
                       f32x16& a0, f32x16& a1, float& lr, float mB, bool diag) {
        f32x16 s;
#pragma unroll
        for (int r = 0; r < 16; r++) s[r] = -mB;     // bias in C-init: MFMA emits S - mB
#pragma unroll
        for (int sub = 0; sub < 4; sub++) s = mfma32x(kf[sub], qf[sub], s);
        if (diag) {
#pragma unroll
            for (int r = 0; r < 16; r++) {
                const int kvl = (r & 3) + 8 * (r >> 2) + (hi ? 4 : 0);
                if (kvl > l31) s[r] = -1e30f;
            }
        }
        float p0 = 0.f, p1 = 0.f;
#pragma unroll
        for (int r = 0; r < 16; r += 2) {
            const float ea = exp2a(s[r]);
            const float eb = exp2a(s[r + 1]);
            s[r] = ea; s[r + 1] = eb;
            p0 += ea; p1 += eb;
        }
        lr += p0 + p1;
        unsigned w0 = cvtpk(s[0], s[1]),  w1 = cvtpk(s[2], s[3]);
        unsigned w2 = cvtpk(s[4], s[5]),  w3 = cvtpk(s[6], s[7]);
        u32x2 r02 = permswap2(w0, w2), r13 = permswap2(w1, w3);
        bf16x8 pf0 = pack4(r02[0], r13[0], r02[1], r13[1]);
        unsigned y0 = cvtpk(s[8], s[9]),   y1 = cvtpk(s[10], s[11]);
        unsigned y2 = cvtpk(s[12], s[13]), y3 = cvtpk(s[14], s[15]);
        u32x2 t02 = permswap2(y0, y2), t13 = permswap2(y1, y3);
        bf16x8 pf1 = pack4(t02[0], t13[0], t02[1], t13[1]);
        a0 = mfma32x(vf00, pf0, a0);
        a0 = mfma32x(vf01, pf1, a0);
        a1 = mfma32x(vf10, pf0, a1);
        a1 = mfma32x(vf11, pf1, a1);
    };

    stageK(0, 0, 0); stageK(1, 0, 1);
    u16x8 v0 = loadV(0), v1 = loadV(1);
    for (int i = 0; i < iters; i++) {
        const int buf = i & 1;
        writeV(buf, 0, v0); writeV(buf, 1, v1);
        __syncthreads();
        if (i + 1 < iters) {
            stageK(2 * i + 2, buf ^ 1, 0); stageK(2 * i + 3, buf ^ 1, 1);
            v0 = loadV(2 * i + 2); v1 = loadV(2 * i + 3);
        }
        const int jt = 2 * i + par;
        if (jt <= t2) {
            const u16* kcur = smem + (buf * 2 + par) * 2048;
            const u16* vcur = smem + 8192 + (buf * 2 + par) * 2560;
            bf16x8 kf[4];
#pragma unroll
            for (int sub = 0; sub < 4; sub++)
                kf[sub] = ldbf8(kcur + l31 * 64 + (((sub * 2 + hi1) ^ (l31 & 7)) * 8));
            const bf16x8 vf00 = ldbf8(vcur + l31 * 40 + hi8);
            const bf16x8 vf01 = ldbf8(vcur + l31 * 40 + 16 + hi8);
            const bf16x8 vf10 = ldbf8(vcur + (32 + l31) * 40 + hi8);
            const bf16x8 vf11 = ldbf8(vcur + (32 + l31) * 40 + 16 + hi8);
            if (jt <= t1) process(qf1, kf, vf00, vf01, vf10, vf11, a1lo, a1hi, l1, mB1, jt == t1);
            process(qf2, kf, vf00, vf01, vf10, vf11, a2lo, a2hi, l2, mB2, jt == t2);
        }
    }
    float l1t = combine_sum(l1), l2t = combine_sum(l2);

    // ---- parity merge (plain add; fixed bound -> no rescale) ----
    float* fm = (float*)smem;
    __syncthreads();
    {
        float* dst = fm + (((pw * 2) + (par ? 0 : 1)) * 64 + lane) * 36;
        if (par) { *(f32x16*)dst = a1lo; *(f32x16*)(dst + 16) = a1hi; dst[32] = l1t; }
        else     { *(f32x16*)dst = a2lo; *(f32x16*)(dst + 16) = a2hi; dst[32] = l2t; }
    }
    __syncthreads();
    {
        const float* src = fm + (((pw * 2) + (par ? 1 : 0)) * 64 + lane) * 36;
        const f32x16 s0 = *(const f32x16*)src;
        const f32x16 s1 = *(const f32x16*)(src + 16);
        if (par) {
#pragma unroll
            for (int r = 0; r < 16; r++) { a2lo[r] += s0[r]; a2hi[r] += s1[r]; }
            l2t += src[32];
        } else {
#pragma unroll
            for (int r = 0; r < 16; r++) { a1lo[r] += s0[r]; a1hi[r] += s1[r]; }
            l1t += src[32];
        }
    }
    __syncthreads();

    // ---- epilogue: O^T -> LDS [32q][72] -> coalesced ----
    auto epi = [&](const f32x16& a0, const f32x16& a1, float lt, int t) {
        const float rl = 1.0f / lt;
        u16* lb = smem + w * 2304;
#pragma unroll
        for (int i = 0; i < 8; i++) {
            const int d = ((2 * i) & 3) + 8 * ((2 * i) >> 2) + (hi ? 4 : 0);
            *(unsigned*)&lb[l31 * 72 + d]      = cvtpk(a0[2 * i] * rl, a0[2 * i + 1] * rl);
            *(unsigned*)&lb[l31 * 72 + 32 + d] = cvtpk(a1[2 * i] * rl, a1[2 * i + 1] * rl);
        }
        asm volatile("s_waitcnt lgkmcnt(0)" ::: "memory");
#pragma unroll
        for (int i = 0; i < 4; i++) {
            const int qq = i * 8 + (lane >> 3), dd = (lane & 7) * 8;
            *(u16x8*)(o + (bS + t * 32 + qq) * 1024 + h * 64 + dd) = *(const u16x8*)&lb[qq * 72 + dd];
        }
    };
    if (par == 0) epi(a1lo, a1hi, l1t, t1);
    else          epi(a2lo, a2hi, l2t, t2);
}

// ---------------- persistent fused pipeline: prep -> QKV-GEMM -> attn -> O-GEMM ----------------
__global__ __launch_bounds__(256, 2) void fused_all(
        const float* __restrict__ x, const float* __restrict__ gamma,
        const float* __restrict__ Wq, const float* __restrict__ Wkv, const float* __restrict__ Wo,
        u16* __restrict__ xn, u16* __restrict__ xb, u16* __restrict__ Wq_t,
        u16* __restrict__ Wkv_t, u16* __restrict__ Wo_t, u16* __restrict__ qb,
        u16* __restrict__ kb, u16* __restrict__ vtb, u16* __restrict__ attb,
        float* __restrict__ kpart, float* __restrict__ out, unsigned* __restrict__ sync, float qscale) {
    __shared__ __align__(16) char SM[50176];          // gemm 49152+1024 ∪ attn 36864 ∪ prep 4224
    const int bid = blockIdx.x, tid = threadIdx.x;

    // phase 0: LN + weight transposes
    for (int u = bid; u < 6272; u += NBLK)
        prep_unit(SM, u, tid, x, gamma, Wq, Wkv, Wo, xn, xb, Wq_t, Wkv_t, Wo_t, qscale);
    gbar(sync + 0, tid);

    // phase 1: Q-GEMM (512 tiles) + KV-GEMM (64 tiles), XCD-swizzled over 576 units
    for (int u = bid; u < 576; u += NBLK) {
        const int lin = (u & 7) * 72 + (u >> 3);
        u16* lds = (u16*)SM;
        float (*kred)[128] = (float(*)[128])(SM + 49152);
        if (lin < 512) gemm_core<0>(lds, kred, xn, Wq_t, qb, nullptr, nullptr, 1024, 1024, lin & 31, lin >> 5, tid);
        else { const int l2 = lin - 512; gemm_core<2>(lds, kred, xb, Wkv_t, kb, kpart, vtb, 128, 1024, l2 & 31, l2 >> 5, tid); }
    }
    gbar(sync + 4, tid);

    // phase 2: attention
    attn_unit((u16*)SM, bid, tid, qb, kb, vtb, kpart, attb);
    gbar(sync + 8, tid);

    // phase 3: O-GEMM (512 tiles)
    {
        const int lin = (bid & 7) * 64 + (bid >> 3);
        gemm_core<1>((u16*)SM, (float(*)[128])(SM + 49152), attb, Wo_t, nullptr, out, nullptr,
                     1024, 1024, lin & 31, lin >> 5, tid);
    }
}

// ---------------- launcher ----------------
extern "C" void kernel_launch(void* const* d_in, const int* in_sizes, int n_in,
                              void* d_out, int out_size, void* d_ws, size_t ws_size,
                              hipStream_t stream) {
    const float* x     = (const float*)d_in[0];
    const float* gamma = (const float*)d_in[1];
    const float* Wq    = (const float*)d_in[2];
    const float* Wkv   = (const float*)d_in[3];
    const float* Wo    = (const float*)d_in[4];
    float* out = (float*)d_out;
    char* ws = (char*)d_ws;

    u16* Wq_t  = (u16*)(ws + 0);             // 2 MB
    u16* Wo_t  = (u16*)(ws + (2u << 20));    // 2 MB
    u16* Wkv_t = (u16*)(ws + (4u << 20));    // 256 KB
    u16* xn    = (u16*)(ws + 4456448u);      // 8 MB
    u16* xb    = (u16*)(ws + 12845056u);     // 8 MB
    u16* qb    = (u16*)(ws + 21233664u);     // 8 MB
    u16* kb    = (u16*)(ws + 29622272u);     // 512 KB
    u16* vtb   = (u16*)(ws + 30146560u);     // 512 KB
    u16* attb  = (u16*)(ws + 30670848u);     // 8 MB
    float* kpart = (float*)(ws + 39059456u); // 32 floats
    unsigned* syncp = (unsigned*)(ws + 39060480u); // 16 u32 barrier counters

    const float qscale = 0.125f * 1.44269504f;   // SCALE * log2(e) folded into Wq
    init_sync<<<1, 64, 0, stream>>>(syncp);
    fused_all<<<NBLK, 256, 0, stream>>>(x, gamma, Wq, Wkv, Wo, xn, xb, Wq_t, Wkv_t, Wo_t,
                                        qb, kb, vtb, attb, kpart, out, syncp, qscale);
}

// Round 14
// 79.355 us; speedup vs baseline: 4.4446x; 4.4446x over previous
//
#include <hip/hip_runtime.h>

typedef unsigned short u16;
typedef __attribute__((ext_vector_type(8))) u16    u16x8;
typedef __attribute__((ext_vector_type(4))) u16    u16x4;
typedef __attribute__((ext_vector_type(2))) unsigned u32x2;
typedef __attribute__((ext_vector_type(4))) unsigned u32x4;
typedef __attribute__((ext_vector_type(8))) __bf16 bf16x8;
typedef __attribute__((ext_vector_type(4))) float  f32x4;
typedef __attribute__((ext_vector_type(16))) float f32x16;

__device__ __forceinline__ u16 f2bf(float f) {
    unsigned u = __float_as_uint(f);
    u += 0x7fffu + ((u >> 16) & 1u);   // RNE
    return (u16)(u >> 16);
}
__device__ __forceinline__ bf16x8 ldbf8(const u16* p) {
    return __builtin_bit_cast(bf16x8, *(const u16x8*)p);
}
__device__ __forceinline__ f32x4 mfma16(bf16x8 a, bf16x8 b, f32x4 c) {
    return __builtin_amdgcn_mfma_f32_16x16x32_bf16(a, b, c, 0, 0, 0);
}
__device__ __forceinline__ f32x16 mfma32x(bf16x8 a, bf16x8 b, f32x16 c) {
    return __builtin_amdgcn_mfma_f32_32x32x16_bf16(a, b, c, 0, 0, 0);
}
__device__ __forceinline__ float exp2a(float x) {
    float r; asm("v_exp_f32 %0, %1" : "=v"(r) : "v"(x)); return r;
}
__device__ __forceinline__ unsigned cvtpk(float lo, float hiv) {
    unsigned r; asm("v_cvt_pk_bf16_f32 %0, %1, %2" : "=v"(r) : "v"(lo), "v"(hiv)); return r;
}
__device__ __forceinline__ u32x2 permswap2(unsigned a, unsigned b) {
    return __builtin_amdgcn_permlane32_swap(a, b, false, false);
}
__device__ __forceinline__ float combine_sum(float x) {   // x + partner-half x (orientation-robust)
    u32x2 pr = permswap2(__float_as_uint(x), __float_as_uint(x));
    return __uint_as_float(pr[0]) + __uint_as_float(pr[1]);
}
__device__ __forceinline__ bf16x8 pack4(unsigned a, unsigned b, unsigned c, unsigned d) {
    union { unsigned u[4]; bf16x8 v; } t; t.u[0] = a; t.u[1] = b; t.u[2] = c; t.u[3] = d; return t.v;
}

// ---------------- prep: 3 weight transposes + LayerNorm, one launch ----------------
__global__ __launch_bounds__(256) void prep_kernel(const float* __restrict__ x, const float* __restrict__ gamma,
                                                   const float* __restrict__ Wq, const float* __restrict__ Wkv,
                                                   const float* __restrict__ Wo, u16* __restrict__ xn,
                                                   u16* __restrict__ xb, u16* __restrict__ Wq_t,
                                                   u16* __restrict__ Wkv_t, u16* __restrict__ Wo_t, float qscale) {
    const int bid = blockIdx.x, tid = threadIdx.x;
    if (bid < 4096) {
        const int row = bid;
        const float4 v = ((const float4*)(x + (size_t)row * 1024))[tid];
        float s  = v.x + v.y + v.z + v.w;
        float s2 = v.x * v.x + v.y * v.y + v.z * v.z + v.w * v.w;
#pragma unroll
        for (int off = 32; off; off >>= 1) { s += __shfl_down(s, off); s2 += __shfl_down(s2, off); }
        __shared__ float red[2][4];
        const int w = tid >> 6, lane = tid & 63;
        if (lane == 0) { red[0][w] = s; red[1][w] = s2; }
        __syncthreads();
        s  = red[0][0] + red[0][1] + red[0][2] + red[0][3];
        s2 = red[1][0] + red[1][1] + red[1][2] + red[1][3];
        const float mu  = s * (1.0f / 1024.0f);
        const float var = s2 * (1.0f / 1024.0f) - mu * mu;
        const float rs  = rsqrtf(var + 1e-5f);
        const float4 g = ((const float4*)gamma)[tid];
        u16x4 on, ob;
        on.x = f2bf((v.x - mu) * rs * g.x); on.y = f2bf((v.y - mu) * rs * g.y);
        on.z = f2bf((v.z - mu) * rs * g.z); on.w = f2bf((v.w - mu) * rs * g.w);
        ob.x = f2bf(v.x); ob.y = f2bf(v.y); ob.z = f2bf(v.z); ob.w = f2bf(v.w);
        ((u16x4*)(xn + (size_t)row * 1024))[tid] = on;
        ((u16x4*)(xb + (size_t)row * 1024))[tid] = ob;
    } else {
        __shared__ float tile[32][33];
        int bt = bid - 4096;
        int by = bt >> 5;
        const float* W; u16* Wt; int N; float scale;
        if (by < 32)      { W = Wq;  Wt = Wq_t;  N = 1024; scale = qscale; }
        else if (by < 36) { W = Wkv; Wt = Wkv_t; N = 128;  by -= 32; scale = 1.0f; }
        else              { W = Wo;  Wt = Wo_t;  N = 1024; by -= 36; scale = 1.0f; }
        const int K = 1024;
        const int kb = (bt & 31) * 32, nb = by * 32;
        const int tx = tid & 31, ty = tid >> 5;      // (32, 8)
#pragma unroll
        for (int i = 0; i < 32; i += 8)
            tile[ty + i][tx] = W[(size_t)(kb + ty + i) * N + nb + tx];
        __syncthreads();
#pragma unroll
        for (int i = 0; i < 32; i += 8)
            Wt[(size_t)(nb + ty + i) * K + kb + tx] = f2bf(tile[tx][ty + i] * scale);
    }
}

// ---------------- GEMM core: C[M,N] = A[M,K] @ Bt[N,K]^T, BM=128 BN=64 BK=64 ----------------
template<int EPI>
__device__ __forceinline__ void gemm_core(u16* lds, float (*kred)[128],
                                          const u16* __restrict__ A, const u16* __restrict__ Bt,
                                          u16* __restrict__ Cb, float* __restrict__ Cf, u16* __restrict__ Cv,
                                          int N, int K, int bx, int by, int tid) {
    constexpr int BM = 128, BN = 64, BK = 64;
    constexpr int WM = 64, WN = 32, FM = 4, FN = 2;
    constexpr int CPR = BK / 8, MS = CPR - 1;
    constexpr int CHA = BM * CPR, CH = (BM + BN) * CPR, ITERS = CH / 256;
    constexpr int LB = (BM + BN) * BK;
    const int m0 = bx * BM, n0 = by * BN;
    const int w = tid >> 6, lane = tid & 63, cl = lane & 15, kg = lane >> 4;
    const int wr = w >> 1, wc = w & 1;

    auto stage = [&](int buf, int k0) {
#pragma unroll
        for (int it = 0; it < ITERS; ++it) {
            int c = it * 256 + tid;
            const u16* g;
            if (c < CHA) { int r = c / CPR, cc = c & MS; g = A  + (size_t)(m0 + r) * K + k0 + ((cc ^ (r & MS)) * 8); }
            else { int c2 = c - CHA; int r = c2 / CPR, cc = c2 & MS; g = Bt + (size_t)(n0 + r) * K + k0 + ((cc ^ (r & MS)) * 8); }
            __builtin_amdgcn_global_load_lds(
                (const __attribute__((address_space(1))) unsigned int*)g,
                (__attribute__((address_space(3))) unsigned int*)&lds[buf * LB + c * 8], 16, 0, 0);
        }
    };

    const f32x4 zero = {0.f, 0.f, 0.f, 0.f};
    f32x4 acc[FM][FN];
#pragma unroll
    for (int m = 0; m < FM; m++)
#pragma unroll
        for (int n = 0; n < FN; n++) acc[m][n] = zero;

    const int KT = K / BK;
    stage(0, 0);
    for (int t = 0; t < KT; ++t) {
        __syncthreads();
        if (t + 1 < KT) stage((t + 1) & 1, (t + 1) * BK);
        const u16* As = &lds[(t & 1) * LB];
        const u16* Bs = &lds[(t & 1) * LB + BM * BK];
#pragma unroll
        for (int s = 0; s < BK / 32; s++) {
            bf16x8 af[FM], bfr[FN];
#pragma unroll
            for (int m = 0; m < FM; m++) {
                const int ra = wr * WM + m * 16 + cl;
                af[m] = ldbf8(As + ra * BK + (((s * 4 + kg) ^ (ra & MS)) * 8));
            }
#pragma unroll
            for (int n = 0; n < FN; n++) {
                const int rb = wc * WN + n * 16 + cl;
                bfr[n] = ldbf8(Bs + rb * BK + (((s * 4 + kg) ^ (rb & MS)) * 8));
            }
#pragma unroll
            for (int m = 0; m < FM; m++)
#pragma unroll
                for (int n = 0; n < FN; n++) acc[m][n] = mfma16(af[m], bfr[n], acc[m][n]);
        }
    }

#pragma unroll
    for (int m = 0; m < FM; m++)
#pragma unroll
        for (int n = 0; n < FN; n++)
#pragma unroll
            for (int r = 0; r < 4; r++) {
                const int row = m0 + wr * WM + m * 16 + kg * 4 + r;
                const int col = n0 + wc * WN + n * 16 + cl;
                const float v = acc[m][n][r];
                if constexpr (EPI == 0) Cb[(size_t)row * N + col] = f2bf(v);
                else if constexpr (EPI == 1) Cf[(size_t)row * N + col] = v;
                else {
                    if (col < 64) Cb[(size_t)row * 64 + col] = f2bf(v);
                    else { int bb = row >> 11, s = row & 2047;
                           Cv[((size_t)bb * 64 + (col - 64)) * 2048 + s] = f2bf(v); }
                }
            }

    if constexpr (EPI == 2) {
        if (n0 == 0) {
            float s2[FM][4];
#pragma unroll
            for (int m = 0; m < FM; m++)
#pragma unroll
                for (int r = 0; r < 4; r++) {
                    float t = 0.f;
#pragma unroll
                    for (int n = 0; n < FN; n++) {
                        const float vb = __uint_as_float(((unsigned)f2bf(acc[m][n][r])) << 16);
                        t = fmaf(vb, vb, t);
                    }
                    s2[m][r] = t;
                }
#pragma unroll
            for (int off = 1; off < 16; off <<= 1)
#pragma unroll
                for (int m = 0; m < FM; m++)
#pragma unroll
                    for (int r = 0; r < 4; r++) s2[m][r] += __shfl_xor(s2[m][r], off);
            if (cl == 0)
#pragma unroll
                for (int m = 0; m < FM; m++)
#pragma unroll
                    for (int r = 0; r < 4; r++) kred[wc][wr * 64 + m * 16 + kg * 4 + r] = s2[m][r];
            __syncthreads();
            if (tid < 64) {
                float t = fmaxf(kred[0][tid] + kred[1][tid], kred[0][tid + 64] + kred[1][tid + 64]);
#pragma unroll
                for (int off = 1; off < 64; off <<= 1) t = fmaxf(t, __shfl_xor(t, off));
                if (tid == 0) Cf[bx] = t;      // Cf = kpart
            }
        }
    }
}

__global__ __launch_bounds__(256, 2) void gemm_qkv(const u16* __restrict__ xn, const u16* __restrict__ Wq_t,
                                                   u16* __restrict__ qb, const u16* __restrict__ xb,
                                                   const u16* __restrict__ Wkv_t, u16* __restrict__ kb,
                                                   u16* __restrict__ vtb, float* __restrict__ kpart) {
    __shared__ __align__(16) u16 lds[2 * 192 * 64];
    __shared__ float kred[2][128];
    const int tid = threadIdx.x;
    const int nwg = gridDim.x;                        // 576, %8==0
    int lin = blockIdx.x;
    lin = (lin & 7) * (nwg >> 3) + (lin >> 3);
    if (lin < 512) gemm_core<0>(lds, kred, xn, Wq_t, qb, nullptr, nullptr, 1024, 1024, lin & 31, lin >> 5, tid);
    else { int l2 = lin - 512; gemm_core<2>(lds, kred, xb, Wkv_t, kb, kpart, vtb, 128, 1024, l2 & 31, l2 >> 5, tid); }
}

__global__ __launch_bounds__(256, 2) void gemm_o(const u16* __restrict__ attb, const u16* __restrict__ Wo_t,
                                                 float* __restrict__ out) {
    __shared__ __align__(16) u16 lds[2 * 192 * 64];
    __shared__ float kred[2][128];
    const int tid = threadIdx.x;
    const int nwg = gridDim.x;                        // 512
    int lin = blockIdx.x;
    lin = (lin & 7) * (nwg >> 3) + (lin >> 3);
    gemm_core<1>(lds, kred, attb, Wo_t, nullptr, out, nullptr, 1024, 1024, lin & 31, lin >> 5, tid);
}

// ---------------- causal flash attention: counted-vmcnt depth-3 pipeline, 4 LDS buffer-sets ------
// Block=(b,h,p); waves=(pair pw)x(kv-parity par); q-tiles t1=2p+pw, t2=63-t1.
// Per iter: vmcnt(8) retires only iter-i loads (i+1,i+2 stay in flight across barrier);
// stage(i+3) targets set (i+3)&3 whose readers (iter i-1) finished before barrier(i).
__global__ __launch_bounds__(256, 2) void attn_fwd(const u16* __restrict__ q, const u16* __restrict__ k,
                                                   const u16* __restrict__ vt, const float* __restrict__ kpart,
                                                   u16* __restrict__ o) {
    constexpr int S = 2048;
    const int bid = blockIdx.x;
    const int p = (bid < 256) ? (bid >> 5) : (15 - ((bid - 256) >> 5));
    const int bh = bid & 31;
    const int h = bh & 15, b = bh >> 4;
    const int tid = threadIdx.x, w = tid >> 6, lane = tid & 63;
    const int pw = w & 1, par = w >> 1;
    const int l31 = lane & 31;
    const bool hi = (lane & 32) != 0;
    const int hi1 = hi ? 1 : 0, hi8 = hi ? 8 : 0;
    const int t1 = 2 * p + pw, t2 = 63 - t1;
    const int iters = 32 - p;                        // >= 17
    const size_t bS = (size_t)b * S;

    // 4 sets x (2 K tiles 2048 u16 + 2 V tiles 2560 u16) = 4 x 9216 u16 = 73728 B
    __shared__ __align__(16) u16 smem[36864];

    auto stageK = [&](int jt, int set, int tl) {
        const int r = tid >> 3, c = tid & 7;
        const u16* gp = k + (bS + jt * 32 + r) * 64 + ((c ^ (r & 7)) * 8);
        __builtin_amdgcn_global_load_lds(
            (const __attribute__((address_space(1))) unsigned int*)gp,
            (__attribute__((address_space(3))) unsigned int*)(smem + set * 9216 + tl * 2048 + tid * 8), 16, 0, 0);
    };
    auto loadVa = [&](int jt) -> u16x8 {             // pinned-order asm load (counted in vmcnt)
        const int rv = tid >> 2, c4 = tid & 3;
        const u16* ap = vt + ((size_t)b * 64 + rv) * S + jt * 32 + c4 * 8;
        u32x4 d;
        asm volatile("global_load_dwordx4 %0, %1, off" : "=v"(d) : "v"(ap) : "memory");
        return __builtin_bit_cast(u16x8, d);
    };
    auto writeV = [&](int set, int tl, u16x8 v) {
        const int rv = tid >> 2, c4 = tid & 3;
        *(u16x8*)(smem + set * 9216 + 4096 + tl * 2560 + rv * 40 + c4 * 8) = v;
    };

    float km = kpart[(b << 4) + (l31 & 15)];
#pragma unroll
    for (int off = 1; off < 16; off <<= 1) km = fmaxf(km, __shfl_xor(km, off));
    const float kmaxb = sqrtf(km);

    bf16x8 qf1[4], qf2[4];
    float mB1, mB2;
    auto qload = [&](int t, bf16x8 (&qf)[4]) -> float {
        const u16* qp = q + (bS + t * 32 + l31) * 1024 + h * 64 + hi8;
        float qn2 = 0.f;
#pragma unroll
        for (int sub = 0; sub < 4; sub++) {
            qf[sub] = ldbf8(qp + sub * 16);
            const u16x8 uv = __builtin_bit_cast(u16x8, qf[sub]);
#pragma unroll
            for (int j = 0; j < 8; j++) {
                const float v = __uint_as_float(((unsigned)uv[j]) << 16);
                qn2 = fmaf(v, v, qn2);
            }
        }
        return sqrtf(combine_sum(qn2)) * kmaxb;
    };
    mB1 = qload(t1, qf1);
    mB2 = qload(t2, qf2);

    f32x16 a1lo, a1hi, a2lo, a2hi;
#pragma unroll
    for (int r = 0; r < 16; r++) { a1lo[r] = 0.f; a1hi[r] = 0.f; a2lo[r] = 0.f; a2hi[r] = 0.f; }
    float l1 = 0.f, l2 = 0.f;

    auto process = [&](const bf16x8 (&qf)[4], const bf16x8 (&kf)[4],
                       const bf16x8& vf00, const bf16x8& vf01, const bf16x8& vf10, const bf16x8& vf11,
                       f32x16& a0, f32x16& a1, float& lr, float mB, bool diag) {
        f32x16 s;
#pragma unroll
        for (int r = 0; r < 16; r++) s[r] = -mB;     // bias in C-init: MFMA emits S - mB
#pragma unroll
        for (int sub = 0; sub < 4; sub++) s = mfma32x(kf[sub], qf[sub], s);
        if (diag) {
#pragma unroll
            for (int r = 0; r < 16; r++) {
                const int kvl = (r & 3) + 8 * (r >> 2) + (hi ? 4 : 0);
                if (kvl > l31) s[r] = -1e30f;
            }
        }
        float p0 = 0.f, p1 = 0.f;
#pragma unroll
        for (int r = 0; r < 16; r += 2) {
            const float ea = exp2a(s[r]);
            const float eb = exp2a(s[r + 1]);
            s[r] = ea; s[r + 1] = eb;
            p0 += ea; p1 += eb;
        }
        lr += p0 + p1;
        unsigned w0 = cvtpk(s[0], s[1]),  w1 = cvtpk(s[2], s[3]);
        unsigned w2 = cvtpk(s[4], s[5]),  w3 = cvtpk(s[6], s[7]);
        u32x2 r02 = permswap2(w0, w2), r13 = permswap2(w1, w3);
        bf16x8 pf0 = pack4(r02[0], r13[0], r02[1], r13[1]);
        unsigned y0 = cvtpk(s[8], s[9]),   y1 = cvtpk(s[10], s[11]);
        unsigned y2 = cvtpk(s[12], s[13]), y3 = cvtpk(s[14], s[15]);
        u32x2 t02 = permswap2(y0, y2), t13 = permswap2(y1, y3);
        bf16x8 pf1 = pack4(t02[0], t13[0], t02[1], t13[1]);
        a0 = mfma32x(vf00, pf0, a0);
        a0 = mfma32x(vf01, pf1, a0);
        a1 = mfma32x(vf10, pf0, a1);
        a1 = mfma32x(vf11, pf1, a1);
    };

    // ---- prologue: stage iters 0,1,2 into sets 0,1,2 (iters >= 17 so no guards) ----
    u16x8 va0, vb0, va1, vb1, va2, vb2, va3, vb3;
    stageK(0, 0, 0); stageK(1, 0, 1); va0 = loadVa(0); vb0 = loadVa(1);
    stageK(2, 1, 0); stageK(3, 1, 1); va1 = loadVa(2); vb1 = loadVa(3);
    stageK(4, 2, 0); stageK(5, 2, 1); va2 = loadVa(4); vb2 = loadVa(5);

#define ABODY(I, SLOT, vaC, vbC, vaN, vbN)                                          \
    if ((I) < iters) {                                                              \
        if ((I) + 2 < iters)      asm volatile("s_waitcnt vmcnt(8)" ::: "memory");  \
        else if ((I) + 1 < iters) asm volatile("s_waitcnt vmcnt(4)" ::: "memory");  \
        else                      asm volatile("s_waitcnt vmcnt(0)" ::: "memory");  \
        writeV(SLOT, 0, vaC); writeV(SLOT, 1, vbC);                                 \
        asm volatile("s_waitcnt lgkmcnt(0)" ::: "memory");                          \
        __builtin_amdgcn_s_barrier();                                               \
        __builtin_amdgcn_sched_barrier(0);                                          \
        if ((I) + 3 < iters) {                                                      \
            stageK(2 * ((I) + 3),     ((SLOT) + 3) & 3, 0);                         \
            stageK(2 * ((I) + 3) + 1, ((SLOT) + 3) & 3, 1);                         \
            vaN = loadVa(2 * ((I) + 3)); vbN = loadVa(2 * ((I) + 3) + 1);           \
        }                                                                           \
        const int jt = 2 * (I) + par;                                               \
        if (jt <= t2) {                                                             \
            const u16* kcur = smem + (SLOT) * 9216 + par * 2048;                    \
            const u16* vcur = smem + (SLOT) * 9216 + 4096 + par * 2560;             \
            bf16x8 kf[4];                                                           \
            _Pragma("unroll")                                                       \
            for (int sub = 0; sub < 4; sub++)                                       \
                kf[sub] = ldbf8(kcur + l31 * 64 + (((sub * 2 + hi1) ^ (l31 & 7)) * 8)); \
            const bf16x8 vf00 = ldbf8(vcur + l31 * 40 + hi8);                       \
            const bf16x8 vf01 = ldbf8(vcur + l31 * 40 + 16 + hi8);                  \
            const bf16x8 vf10 = ldbf8(vcur + (32 + l31) * 40 + hi8);                \
            const bf16x8 vf11 = ldbf8(vcur + (32 + l31) * 40 + 16 + hi8);           \
            if (jt <= t1) process(qf1, kf, vf00, vf01, vf10, vf11, a1lo, a1hi, l1, mB1, jt == t1); \
            process(qf2, kf, vf00, vf01, vf10, vf11, a2lo, a2hi, l2, mB2, jt == t2); \
        }                                                                           \
    }

    for (int ii = 0; ii < 32; ii += 4) {
        ABODY(ii + 0, 0, va0, vb0, va3, vb3)
        ABODY(ii + 1, 1, va1, vb1, va0, vb0)
        ABODY(ii + 2, 2, va2, vb2, va1, vb1)
        ABODY(ii + 3, 3, va3, vb3, va2, vb2)
    }
#undef ABODY
    asm volatile("s_waitcnt vmcnt(0)" ::: "memory");  // all stray stage writes landed
    float l1t = combine_sum(l1), l2t = combine_sum(l2);

    // ---- parity merge (plain add; fixed bound -> no rescale) ----
    float* fm = (float*)smem;
    __syncthreads();                                  // all stage-buffer reads done; safe to alias
    {
        float* dst = fm + (((pw * 2) + (par ? 0 : 1)) * 64 + lane) * 36;
        if (par) { *(f32x16*)dst = a1lo; *(f32x16*)(dst + 16) = a1hi; dst[32] = l1t; }
        else     { *(f32x16*)dst = a2lo; *(f32x16*)(dst + 16) = a2hi; dst[32] = l2t; }
    }
    __syncthreads();
    {
        const float* src = fm + (((pw * 2) + (par ? 1 : 0)) * 64 + lane) * 36;
        const f32x16 s0 = *(const f32x16*)src;
        const f32x16 s1 = *(const f32x16*)(src + 16);
        if (par) {
#pragma unroll
            for (int r = 0; r < 16; r++) { a2lo[r] += s0[r]; a2hi[r] += s1[r]; }
            l2t += src[32];
        } else {
#pragma unroll
            for (int r = 0; r < 16; r++) { a1lo[r] += s0[r]; a1hi[r] += s1[r]; }
            l1t += src[32];
        }
    }
    __syncthreads();

    // ---- epilogue: O^T -> LDS [32q][72] -> coalesced ----
    auto epi = [&](const f32x16& a0, const f32x16& a1, float lt, int t) {
        const float rl = 1.0f / lt;
        u16* lb = smem + w * 2304;
#pragma unroll
        for (int i = 0; i < 8; i++) {
            const int d = ((2 * i) & 3) + 8 * ((2 * i) >> 2) + (hi ? 4 : 0);
            *(unsigned*)&lb[l31 * 72 + d]      = cvtpk(a0[2 * i] * rl, a0[2 * i + 1] * rl);
            *(unsigned*)&lb[l31 * 72 + 32 + d] = cvtpk(a1[2 * i] * rl, a1[2 * i + 1] * rl);
        }
        asm volatile("s_waitcnt lgkmcnt(0)" ::: "memory");
#pragma unroll
        for (int i = 0; i < 4; i++) {
            const int qq = i * 8 + (lane >> 3), dd = (lane & 7) * 8;
            *(u16x8*)(o + (bS + t * 32 + qq) * 1024 + h * 64 + dd) = *(const u16x8*)&lb[qq * 72 + dd];
        }
    };
    if (par == 0) epi(a1lo, a1hi, l1t, t1);
    else          epi(a2lo, a2hi, l2t, t2);
}

// ---------------- launcher ----------------
extern "C" void kernel_launch(void* const* d_in, const int* in_sizes, int n_in,
                              void* d_out, int out_size, void* d_ws, size_t ws_size,
                              hipStream_t stream) {
    const float* x     = (const float*)d_in[0];
    const float* gamma = (const float*)d_in[1];
    const float* Wq    = (const float*)d_in[2];
    const float* Wkv   = (const float*)d_in[3];
    const float* Wo    = (const float*)d_in[4];
    float* out = (float*)d_out;
    char* ws = (char*)d_ws;

    u16* Wq_t  = (u16*)(ws + 0);             // 2 MB
    u16* Wo_t  = (u16*)(ws + (2u << 20));    // 2 MB
    u16* Wkv_t = (u16*)(ws + (4u << 20));    // 256 KB
    u16* xn    = (u16*)(ws + 4456448u);      // 8 MB
    u16* xb    = (u16*)(ws + 12845056u);     // 8 MB
    u16* qb    = (u16*)(ws + 21233664u);     // 8 MB
    u16* kb    = (u16*)(ws + 29622272u);     // 512 KB
    u16* vtb   = (u16*)(ws + 30146560u);     // 512 KB
    u16* attb  = (u16*)(ws + 30670848u);     // 8 MB
    float* kpart = (float*)(ws + 39059456u); // 32 floats

    const float qscale = 0.125f * 1.44269504f;   // SCALE * log2(e) folded into Wq
    prep_kernel<<<4096 + 2176, 256, 0, stream>>>(x, gamma, Wq, Wkv, Wo, xn, xb, Wq_t, Wkv_t, Wo_t, qscale);
    gemm_qkv<<<576, 256, 0, stream>>>(xn, Wq_t, qb, xb, Wkv_t, kb, vtb, kpart);
    attn_fwd<<<512, 256, 0, stream>>>(qb, kb, vtb, kpart, attb);
    gemm_o<<<512, 256, 0, stream>>>(attb, Wo_t, out);
}